// Round 6
// baseline (762.536 us; speedup 1.0000x reference)
//
#include <hip/hip_runtime.h>
#include <hip/hip_bf16.h>
#include <hip/hip_fp16.h>

typedef _Float16 half8 __attribute__((ext_vector_type(8)));
typedef _Float16 half4 __attribute__((ext_vector_type(4)));
typedef __fp16 fp16x2 __attribute__((ext_vector_type(2)));
typedef float floatx4 __attribute__((ext_vector_type(4)));

#define HID 128
#define TILE_M 64

__device__ __forceinline__ float fast_silu(float v) {
    float e = __expf(-v);
    return v * __builtin_amdgcn_rcpf(1.f + e);
}

__device__ __forceinline__ unsigned int pk2(float a, float b) {
    fp16x2 h = __builtin_amdgcn_cvt_pkrtz(a, b);
    return __builtin_bit_cast(unsigned int, h);
}

__device__ __forceinline__ float dot2f(fp16x2 a, fp16x2 b, float c) {
#if __has_builtin(__builtin_amdgcn_fdot2)
    return __builtin_amdgcn_fdot2(a, b, c, false);
#else
    return fmaf((float)a[0], (float)b[0], fmaf((float)a[1], (float)b[1], c));
#endif
}

// ---------------------------------------------------------------------------
// Kernel 1: node_emb = [x|pos|0-pad] @ [Wa;Wp;0] + (ba+bp), all-MFMA, no LDS.
// Swapped operands: mfma(w_frag, a_frag) -> D[m=col][n=node]; lane stores 8B.
// ---------------------------------------------------------------------------
__global__ __launch_bounds__(256) void node_emb_kernel(
    const float* __restrict__ x, const float* __restrict__ pos,
    const float* __restrict__ Wa, const float* __restrict__ ba,
    const float* __restrict__ Wp, const float* __restrict__ bp,
    _Float16* __restrict__ nodeEmb, int N)
{
    const int wave = threadIdx.x >> 6;
    const int lane = threadIdx.x & 63;
    const int quad = lane >> 4;
    const int l16  = lane & 15;

    // B-frag (weights): wf[ct][j] = W[k=quad*8+j][col=ct*16+l16], K padded 19->32
    half8 wf[8];
    floatx4 bias[8];
    #pragma unroll
    for (int ct = 0; ct < 8; ++ct) {
        int col = ct * 16 + l16;
        #pragma unroll
        for (int j = 0; j < 8; ++j) {
            int k = quad * 8 + j;
            float w = 0.f;
            if (k < 16) w = Wa[k * HID + col];
            else if (k < 19) w = Wp[(k - 16) * HID + col];
            wf[ct][j] = (_Float16)w;
        }
        #pragma unroll
        for (int i = 0; i < 4; ++i) {
            int c2 = ct * 16 + quad * 4 + i;
            bias[ct][i] = ba[c2] + bp[c2];
        }
    }

    int nTiles = (N + 63) >> 6;
    for (int tile = blockIdx.x * 4 + wave; tile < nTiles; tile += gridDim.x * 4) {
        half8 af[4];
        #pragma unroll
        for (int rt = 0; rt < 4; ++rt) {
            int node = tile * 64 + rt * 16 + l16;
            int nd = node < N ? node : N - 1;
            half8 a = (half8){0, 0, 0, 0, 0, 0, 0, 0};
            if (quad < 2) {
                const float* xp = x + (size_t)nd * 16 + quad * 8;
                float4 v0 = *(const float4*)xp;
                float4 v1 = *(const float4*)(xp + 4);
                a[0] = (_Float16)v0.x; a[1] = (_Float16)v0.y;
                a[2] = (_Float16)v0.z; a[3] = (_Float16)v0.w;
                a[4] = (_Float16)v1.x; a[5] = (_Float16)v1.y;
                a[6] = (_Float16)v1.z; a[7] = (_Float16)v1.w;
            } else if (quad == 2) {
                const float* pp = pos + (size_t)nd * 3;
                a[0] = (_Float16)pp[0]; a[1] = (_Float16)pp[1]; a[2] = (_Float16)pp[2];
            }
            af[rt] = a;
        }
        #pragma unroll
        for (int ct = 0; ct < 8; ++ct) {
            #pragma unroll
            for (int rt = 0; rt < 4; ++rt) {
                int node = tile * 64 + rt * 16 + l16;
                floatx4 d = bias[ct];
                d = __builtin_amdgcn_mfma_f32_16x16x32_f16(wf[ct], af[rt], d, 0, 0, 0);
                if (node < N) {
                    half4 hv;
                    hv[0] = (_Float16)d[0]; hv[1] = (_Float16)d[1];
                    hv[2] = (_Float16)d[2]; hv[3] = (_Float16)d[3];
                    *(half4*)(nodeEmb + (size_t)node * HID + ct * 16 + quad * 4) = hv;
                }
            }
        }
    }
}

// ---------------------------------------------------------------------------
// Kernel 2: per-edge MLP. 64 edges/tile, async DMA gathers, XOR-swizzled
// sA and sH1, 2 barriers/tile. Layer 3 in registers (dot2 + shfl reduce),
// final cross-wave reduce deferred one tile (pf buffer). LDS 52.3 KB -> 3/CU.
// ---------------------------------------------------------------------------
__global__ __launch_bounds__(256, 3) void edge_mlp_kernel(
    const _Float16* __restrict__ nodeEmb,
    const float* __restrict__ pos,
    const int* __restrict__ eidx,          // [2][E]
    const float* __restrict__ W1, const float* __restrict__ b1,   // [257][128]
    const float* __restrict__ W2, const float* __restrict__ b2,   // [128][128]
    const float* __restrict__ W3, const float* __restrict__ b3,   // [128][4]
    float* __restrict__ out, int E, int nTiles)
{
    __shared__ __align__(16) _Float16 sA[2 * TILE_M * HID];   // 32 KB, XOR swizzle
    __shared__ __align__(16) _Float16 sH1[TILE_M * HID];      // 16 KB, XOR swizzle
    __shared__ float pf[4][TILE_M][4];                        // 4 KB partials
    __shared__ float sDist[TILE_M];

    const int t    = threadIdx.x;
    const int wave = t >> 6;
    const int lane = t & 63;
    const int quad = lane >> 4;
    const int l16  = lane & 15;
    const int colbase = wave * 32;

    // ---- weight fragments ----
    half8 w1f[8][2];
    half8 w2f[4][2];
    fp16x2 w3h[2][2][4];   // [ct][pair][n]: cols (base, base+1)
    float w1c[2][4], b1f[2][4], b2f[2][4];
    #pragma unroll
    for (int ct = 0; ct < 2; ++ct) {
        int col = colbase + ct * 16 + l16;
        #pragma unroll
        for (int kc = 0; kc < 8; ++kc)
            #pragma unroll
            for (int j = 0; j < 8; ++j)
                w1f[kc][ct][j] = (_Float16)W1[(kc * 32 + quad * 8 + j) * HID + col];
        #pragma unroll
        for (int kc = 0; kc < 4; ++kc)
            #pragma unroll
            for (int j = 0; j < 8; ++j)
                w2f[kc][ct][j] = (_Float16)W2[(kc * 32 + quad * 8 + j) * HID + col];
        #pragma unroll
        for (int i = 0; i < 4; ++i) {
            int c2 = colbase + ct * 16 + quad * 4 + i;
            w1c[ct][i] = W1[256 * HID + c2];
            b1f[ct][i] = b1[c2];
            b2f[ct][i] = b2[c2];
        }
        #pragma unroll
        for (int pr = 0; pr < 2; ++pr) {
            int c0 = colbase + ct * 16 + quad * 4 + pr * 2;
            #pragma unroll
            for (int n = 0; n < 4; ++n) {
                fp16x2 h;
                h[0] = (__fp16)W3[c0 * 4 + n];
                h[1] = (__fp16)W3[(c0 + 1) * 4 + n];
                w3h[ct][pr][n] = h;
            }
        }
    }
    const float b3n = b3[t & 3];

    int nid[8];
    float dpre = 0.f;

    auto load_nid = [&](int tl) {
        int eb = tl * TILE_M;
        #pragma unroll
        for (int i = 0; i < 8; ++i) {
            int cid = i * 256 + t;
            int row = cid >> 4;              // 0..127
            int r   = row & 63;
            int e   = eb + r; if (e >= E) e = E - 1;
            nid[i] = (row >> 6) ? eidx[(size_t)E + e] : eidx[e];
        }
    };
    auto load_dist = [&](int tl) -> float {
        if (t >= TILE_M) return 0.f;
        int e = tl * TILE_M + t; if (e >= E) e = E - 1;
        int s = eidx[e], d = eidx[(size_t)E + e];
        float dx = pos[3 * (size_t)s]     - pos[3 * (size_t)d];
        float dy = pos[3 * (size_t)s + 1] - pos[3 * (size_t)d + 1];
        float dz = pos[3 * (size_t)s + 2] - pos[3 * (size_t)d + 2];
        return sqrtf(dx * dx + dy * dy + dz * dz);
    };
    auto dma_issue = [&]() {
        #pragma unroll
        for (int i = 0; i < 8; ++i) {
            int cid = i * 256 + t;
            int row = cid >> 4;
            int cg  = (cid & 15) ^ (row & 15);      // XOR swizzle
            const _Float16* gp = nodeEmb + (size_t)nid[i] * HID + cg * 8;
            __builtin_amdgcn_global_load_lds(
                (__attribute__((address_space(1))) void*)gp,
                (__attribute__((address_space(3))) void*)&sA[(i * 256 + (t & 192)) * 8],
                16, 0, 0);
        }
    };

    bool havePrev = false;
    int prevEbase = 0;
    int tile = blockIdx.x;
    if (tile < nTiles) {
        load_nid(tile);
        dpre = load_dist(tile);
        dma_issue();
    }

    for (; tile < nTiles; tile += gridDim.x) {
        const int ebase = tile * TILE_M;
        if (t < TILE_M) sDist[t] = dpre;
        __syncthreads();                     // B1: sA(T), sDist(T), pf(T-1) ready

        // ---- final reduce of tile T-1 (reads pf, writes out) ----
        if (havePrev) {
            int m = t >> 2, n = t & 3;
            float s = pf[0][m][n] + pf[1][m][n] + pf[2][m][n] + pf[3][m][n] + b3n;
            int e = prevEbase + m;
            if (e < E) out[(size_t)e * 4 + n] = s;
        }

        // ---- prefetch next tile metadata ----
        int nxt = tile + gridDim.x;
        if (nxt < nTiles) {
            load_nid(nxt);
            dpre = load_dist(nxt);
        }

        // ---- layer 1 ----
        floatx4 acc[2][4];
        #pragma unroll
        for (int ct = 0; ct < 2; ++ct)
            #pragma unroll
            for (int rt = 0; rt < 4; ++rt) {
                acc[ct][rt][0] = b1f[ct][0]; acc[ct][rt][1] = b1f[ct][1];
                acc[ct][rt][2] = b1f[ct][2]; acc[ct][rt][3] = b1f[ct][3];
            }
        #pragma unroll
        for (int kc = 0; kc < 8; ++kc) {
            int hf   = kc >> 2;
            int cg   = (kc & 3) * 4 + quad;
            int slot = (cg ^ l16) * 8;
            const _Float16* base = &sA[(hf * TILE_M + l16) * HID + slot];
            half8 a0 = *(const half8*)(base + 0 * 16 * HID);
            half8 a1 = *(const half8*)(base + 1 * 16 * HID);
            half8 a2 = *(const half8*)(base + 2 * 16 * HID);
            half8 a3 = *(const half8*)(base + 3 * 16 * HID);
            acc[0][0] = __builtin_amdgcn_mfma_f32_16x16x32_f16(w1f[kc][0], a0, acc[0][0], 0, 0, 0);
            acc[0][1] = __builtin_amdgcn_mfma_f32_16x16x32_f16(w1f[kc][0], a1, acc[0][1], 0, 0, 0);
            acc[0][2] = __builtin_amdgcn_mfma_f32_16x16x32_f16(w1f[kc][0], a2, acc[0][2], 0, 0, 0);
            acc[0][3] = __builtin_amdgcn_mfma_f32_16x16x32_f16(w1f[kc][0], a3, acc[0][3], 0, 0, 0);
            acc[1][0] = __builtin_amdgcn_mfma_f32_16x16x32_f16(w1f[kc][1], a0, acc[1][0], 0, 0, 0);
            acc[1][1] = __builtin_amdgcn_mfma_f32_16x16x32_f16(w1f[kc][1], a1, acc[1][1], 0, 0, 0);
            acc[1][2] = __builtin_amdgcn_mfma_f32_16x16x32_f16(w1f[kc][1], a2, acc[1][2], 0, 0, 0);
            acc[1][3] = __builtin_amdgcn_mfma_f32_16x16x32_f16(w1f[kc][1], a3, acc[1][3], 0, 0, 0);
        }
        // epilogue 1 -> sH1 (XOR-swizzled uint2 writes)
        #pragma unroll
        for (int rt = 0; rt < 4; ++rt) {
            int m = rt * 16 + l16;
            float d = sDist[m];
            #pragma unroll
            for (int ct = 0; ct < 2; ++ct) {
                float v0 = fast_silu(fmaf(d, w1c[ct][0], acc[ct][rt][0]));
                float v1 = fast_silu(fmaf(d, w1c[ct][1], acc[ct][rt][1]));
                float v2 = fast_silu(fmaf(d, w1c[ct][2], acc[ct][rt][2]));
                float v3 = fast_silu(fmaf(d, w1c[ct][3], acc[ct][rt][3]));
                uint2 w;
                w.x = pk2(v0, v1);
                w.y = pk2(v2, v3);
                int cgb  = wave * 4 + ct * 2 + (quad >> 1);
                int slot = cgb ^ l16;
                *(uint2*)&sH1[m * HID + slot * 8 + (quad & 1) * 4] = w;
            }
        }
        __syncthreads();                     // B2: sH1 visible, sA reads done

        // ---- async DMA for next tile ----
        if (nxt < nTiles) dma_issue();

        // ---- layer 2 ----
        floatx4 acc2[2][4];
        #pragma unroll
        for (int ct = 0; ct < 2; ++ct)
            #pragma unroll
            for (int rt = 0; rt < 4; ++rt) {
                acc2[ct][rt][0] = b2f[ct][0]; acc2[ct][rt][1] = b2f[ct][1];
                acc2[ct][rt][2] = b2f[ct][2]; acc2[ct][rt][3] = b2f[ct][3];
            }
        #pragma unroll
        for (int kc = 0; kc < 4; ++kc) {
            int slot = ((kc * 4 + quad) ^ l16) * 8;
            half8 a0 = *(const half8*)&sH1[(0 * 16 + l16) * HID + slot];
            half8 a1 = *(const half8*)&sH1[(1 * 16 + l16) * HID + slot];
            half8 a2 = *(const half8*)&sH1[(2 * 16 + l16) * HID + slot];
            half8 a3 = *(const half8*)&sH1[(3 * 16 + l16) * HID + slot];
            acc2[0][0] = __builtin_amdgcn_mfma_f32_16x16x32_f16(w2f[kc][0], a0, acc2[0][0], 0, 0, 0);
            acc2[0][1] = __builtin_amdgcn_mfma_f32_16x16x32_f16(w2f[kc][0], a1, acc2[0][1], 0, 0, 0);
            acc2[0][2] = __builtin_amdgcn_mfma_f32_16x16x32_f16(w2f[kc][0], a2, acc2[0][2], 0, 0, 0);
            acc2[0][3] = __builtin_amdgcn_mfma_f32_16x16x32_f16(w2f[kc][0], a3, acc2[0][3], 0, 0, 0);
            acc2[1][0] = __builtin_amdgcn_mfma_f32_16x16x32_f16(w2f[kc][1], a0, acc2[1][0], 0, 0, 0);
            acc2[1][1] = __builtin_amdgcn_mfma_f32_16x16x32_f16(w2f[kc][1], a1, acc2[1][1], 0, 0, 0);
            acc2[1][2] = __builtin_amdgcn_mfma_f32_16x16x32_f16(w2f[kc][1], a2, acc2[1][2], 0, 0, 0);
            acc2[1][3] = __builtin_amdgcn_mfma_f32_16x16x32_f16(w2f[kc][1], a3, acc2[1][3], 0, 0, 0);
        }

        // ---- layer 3 in registers: silu -> dot2 partials -> quad reduce -> pf
        #pragma unroll
        for (int rt = 0; rt < 4; ++rt) {
            int m = rt * 16 + l16;
            float p0 = 0.f, p1 = 0.f, p2 = 0.f, p3 = 0.f;
            #pragma unroll
            for (int ct = 0; ct < 2; ++ct) {
                float v0 = fast_silu(acc2[ct][rt][0]);
                float v1 = fast_silu(acc2[ct][rt][1]);
                float v2 = fast_silu(acc2[ct][rt][2]);
                float v3 = fast_silu(acc2[ct][rt][3]);
                fp16x2 hA = __builtin_amdgcn_cvt_pkrtz(v0, v1);
                fp16x2 hB = __builtin_amdgcn_cvt_pkrtz(v2, v3);
                p0 = dot2f(hA, w3h[ct][0][0], p0); p0 = dot2f(hB, w3h[ct][1][0], p0);
                p1 = dot2f(hA, w3h[ct][0][1], p1); p1 = dot2f(hB, w3h[ct][1][1], p1);
                p2 = dot2f(hA, w3h[ct][0][2], p2); p2 = dot2f(hB, w3h[ct][1][2], p2);
                p3 = dot2f(hA, w3h[ct][0][3], p3); p3 = dot2f(hB, w3h[ct][1][3], p3);
            }
            p0 += __shfl_xor(p0, 16); p0 += __shfl_xor(p0, 32);
            p1 += __shfl_xor(p1, 16); p1 += __shfl_xor(p1, 32);
            p2 += __shfl_xor(p2, 16); p2 += __shfl_xor(p2, 32);
            p3 += __shfl_xor(p3, 16); p3 += __shfl_xor(p3, 32);
            if (quad == 0) {
                float4 o = {p0, p1, p2, p3};
                *(float4*)&pf[wave][m][0] = o;
            }
        }
        havePrev = true;
        prevEbase = ebase;
    }

    // ---- flush: final reduce of the last tile ----
    if (havePrev) {
        __syncthreads();
        int m = t >> 2, n = t & 3;
        float s = pf[0][m][n] + pf[1][m][n] + pf[2][m][n] + pf[3][m][n] + b3n;
        int e = prevEbase + m;
        if (e < E) out[(size_t)e * 4 + n] = s;
    }
}

extern "C" void kernel_launch(void* const* d_in, const int* in_sizes, int n_in,
                              void* d_out, int out_size, void* d_ws, size_t ws_size,
                              hipStream_t stream) {
    const float* x   = (const float*)d_in[0];
    const float* pos = (const float*)d_in[1];
    const int*  eidx = (const int*)d_in[2];
    const float* Wa = (const float*)d_in[3];
    const float* ba = (const float*)d_in[4];
    const float* Wp = (const float*)d_in[5];
    const float* bp = (const float*)d_in[6];
    const float* W1 = (const float*)d_in[7];
    const float* b1 = (const float*)d_in[8];
    const float* W2 = (const float*)d_in[9];
    const float* b2 = (const float*)d_in[10];
    const float* W3 = (const float*)d_in[11];
    const float* b3 = (const float*)d_in[12];
    float* out = (float*)d_out;

    int N = in_sizes[0] / 16;   // ATOM_DIM
    int E = in_sizes[2] / 2;

    _Float16* nodeEmb = (_Float16*)d_ws;   // N*128 fp16 = 25.6 MB

    int nodeTiles = (N + 63) / 64;
    int nodeBlocks = (nodeTiles + 3) / 4;
    node_emb_kernel<<<nodeBlocks, 256, 0, stream>>>(x, pos, Wa, ba, Wp, bp, nodeEmb, N);

    int nTiles = (E + TILE_M - 1) / TILE_M;
    edge_mlp_kernel<<<768, 256, 0, stream>>>(nodeEmb, pos, eidx,
                                             W1, b1, W2, b2, W3, b3,
                                             out, E, nTiles);
}

// Round 7
// 416.022 us; speedup vs baseline: 1.8329x; 1.8329x over previous
//
#include <hip/hip_runtime.h>
#include <hip/hip_bf16.h>
#include <hip/hip_fp16.h>

typedef _Float16 half8 __attribute__((ext_vector_type(8)));
typedef _Float16 half4 __attribute__((ext_vector_type(4)));
typedef __fp16 fp16x2 __attribute__((ext_vector_type(2)));
typedef float floatx4 __attribute__((ext_vector_type(4)));

#define HID 128
#define TILE_M 32

__device__ __forceinline__ float fast_silu(float v) {
    float e = __expf(-v);
    return v * __builtin_amdgcn_rcpf(1.f + e);
}

__device__ __forceinline__ unsigned int pk2(float a, float b) {
    fp16x2 h = __builtin_amdgcn_cvt_pkrtz(a, b);
    return __builtin_bit_cast(unsigned int, h);
}

__device__ __forceinline__ float dot2f(fp16x2 a, fp16x2 b, float c) {
#if __has_builtin(__builtin_amdgcn_fdot2)
    return __builtin_amdgcn_fdot2(a, b, c, false);
#else
    return fmaf((float)a[0], (float)b[0], fmaf((float)a[1], (float)b[1], c));
#endif
}

// LDS-only barrier: waits local ops but leaves global_load_lds (vmcnt) in
// flight. Use ONLY where the barrier guards LDS-LDS hazards exclusively.
__device__ __forceinline__ void barrier_lds_only() {
    asm volatile("s_waitcnt lgkmcnt(0)\n\ts_barrier" ::: "memory");
}

// ---------------------------------------------------------------------------
// Kernel 1: node_emb = [x|pos|0-pad] @ [Wa;Wp;0] + (ba+bp). Block handles a
// 64-node tile via MFMA; output assembled in padded LDS, stored coalesced.
// ---------------------------------------------------------------------------
#define LDO 136
__global__ __launch_bounds__(256) void node_emb_kernel(
    const float* __restrict__ x, const float* __restrict__ pos,
    const float* __restrict__ Wa, const float* __restrict__ ba,
    const float* __restrict__ Wp, const float* __restrict__ bp,
    _Float16* __restrict__ nodeEmb, int N)
{
    __shared__ __align__(16) _Float16 sOut[64 * LDO];   // 17 KB
    const int t    = threadIdx.x;
    const int wave = t >> 6;
    const int lane = t & 63;
    const int quad = lane >> 4;
    const int l16  = lane & 15;

    // wave owns cols [wave*32, +32): B-frag wf[ct][j] = W[k=quad*8+j][col]
    half8 wf[2];
    floatx4 bias[2];
    #pragma unroll
    for (int ct = 0; ct < 2; ++ct) {
        int col = wave * 32 + ct * 16 + l16;
        #pragma unroll
        for (int j = 0; j < 8; ++j) {
            int k = quad * 8 + j;
            float w = 0.f;
            if (k < 16) w = Wa[k * HID + col];
            else if (k < 19) w = Wp[(k - 16) * HID + col];
            wf[ct][j] = (_Float16)w;
        }
        #pragma unroll
        for (int i = 0; i < 4; ++i) {
            int c2 = wave * 32 + ct * 16 + quad * 4 + i;
            bias[ct][i] = ba[c2] + bp[c2];
        }
    }

    int nTiles = (N + 63) >> 6;
    for (int tile = blockIdx.x; tile < nTiles; tile += gridDim.x) {
        int base = tile * 64;
        half8 af[4];
        #pragma unroll
        for (int rt = 0; rt < 4; ++rt) {
            int node = base + rt * 16 + l16;
            int nd = node < N ? node : N - 1;
            half8 a = (half8){0, 0, 0, 0, 0, 0, 0, 0};
            if (quad < 2) {
                const float* xp = x + (size_t)nd * 16 + quad * 8;
                float4 v0 = *(const float4*)xp;
                float4 v1 = *(const float4*)(xp + 4);
                a[0] = (_Float16)v0.x; a[1] = (_Float16)v0.y;
                a[2] = (_Float16)v0.z; a[3] = (_Float16)v0.w;
                a[4] = (_Float16)v1.x; a[5] = (_Float16)v1.y;
                a[6] = (_Float16)v1.z; a[7] = (_Float16)v1.w;
            } else if (quad == 2) {
                const float* pp = pos + (size_t)nd * 3;
                a[0] = (_Float16)pp[0]; a[1] = (_Float16)pp[1]; a[2] = (_Float16)pp[2];
            }
            af[rt] = a;
        }
        #pragma unroll
        for (int ct = 0; ct < 2; ++ct)
            #pragma unroll
            for (int rt = 0; rt < 4; ++rt) {
                floatx4 d = bias[ct];
                d = __builtin_amdgcn_mfma_f32_16x16x32_f16(wf[ct], af[rt], d, 0, 0, 0);
                half4 hv;
                hv[0] = (_Float16)d[0]; hv[1] = (_Float16)d[1];
                hv[2] = (_Float16)d[2]; hv[3] = (_Float16)d[3];
                *(half4*)&sOut[(rt * 16 + l16) * LDO + wave * 32 + ct * 16 + quad * 4] = hv;
            }
        __syncthreads();
        #pragma unroll
        for (int p = 0; p < 4; ++p) {
            int idx = p * 256 + t;           // 1024 chunks of 8 halves
            int r = idx >> 4, c = idx & 15;
            int node = base + r;
            if (node < N)
                *(half8*)(nodeEmb + (size_t)node * HID + c * 8) =
                    *(const half8*)&sOut[r * LDO + c * 8];
        }
        __syncthreads();
    }
}

// ---------------------------------------------------------------------------
// Kernel 2: per-edge MLP. 32 edges/tile, double-buffered sA with DMA issued
// one FULL tile ahead (lgkm-only B2 keeps the DMA in flight), XOR-swizzled
// sA/sH1, layer 3 in registers, final reduce deferred one tile.
// ---------------------------------------------------------------------------
__global__ __launch_bounds__(256, 2) void edge_mlp_kernel(
    const _Float16* __restrict__ nodeEmb,
    const float* __restrict__ pos,
    const int* __restrict__ eidx,          // [2][E]
    const float* __restrict__ W1, const float* __restrict__ b1,   // [257][128]
    const float* __restrict__ W2, const float* __restrict__ b2,   // [128][128]
    const float* __restrict__ W3, const float* __restrict__ b3,   // [128][4]
    float* __restrict__ out, int E, int nTiles)
{
    __shared__ __align__(16) _Float16 sA[2][2 * TILE_M * HID];  // 2 x 16 KB
    __shared__ __align__(16) _Float16 sH1[TILE_M * HID];        // 8 KB
    __shared__ float pf[4][TILE_M][4];                          // 2 KB
    __shared__ float sDist[TILE_M];

    const int t    = threadIdx.x;
    const int wave = t >> 6;
    const int lane = t & 63;
    const int quad = lane >> 4;
    const int l16  = lane & 15;
    const int colbase = wave * 32;

    // ---- weight fragments ----
    half8 w1f[8][2];
    half8 w2f[4][2];
    fp16x2 w3h[2][2][4];
    float w1c[2][4], b1f[2][4], b2f[2][4];
    #pragma unroll
    for (int ct = 0; ct < 2; ++ct) {
        int col = colbase + ct * 16 + l16;
        #pragma unroll
        for (int kc = 0; kc < 8; ++kc)
            #pragma unroll
            for (int j = 0; j < 8; ++j)
                w1f[kc][ct][j] = (_Float16)W1[(kc * 32 + quad * 8 + j) * HID + col];
        #pragma unroll
        for (int kc = 0; kc < 4; ++kc)
            #pragma unroll
            for (int j = 0; j < 8; ++j)
                w2f[kc][ct][j] = (_Float16)W2[(kc * 32 + quad * 8 + j) * HID + col];
        #pragma unroll
        for (int i = 0; i < 4; ++i) {
            int c2 = colbase + ct * 16 + quad * 4 + i;
            w1c[ct][i] = W1[256 * HID + c2];
            b1f[ct][i] = b1[c2];
            b2f[ct][i] = b2[c2];
        }
        #pragma unroll
        for (int pr = 0; pr < 2; ++pr) {
            int c0 = colbase + ct * 16 + quad * 4 + pr * 2;
            #pragma unroll
            for (int n = 0; n < 4; ++n) {
                fp16x2 h;
                h[0] = (__fp16)W3[c0 * 4 + n];
                h[1] = (__fp16)W3[(c0 + 1) * 4 + n];
                w3h[ct][pr][n] = h;
            }
        }
    }
    const float b3n = b3[t & 3];

    int nid[4];
    float dpre = 0.f;

    auto load_nid = [&](int tl) {
        int eb = tl * TILE_M;
        #pragma unroll
        for (int i = 0; i < 4; ++i) {
            int cid = i * 256 + t;           // 0..1023 chunks
            int row = cid >> 4;              // 0..63: 0-31 src, 32-63 dst
            int r   = row & 31;
            int e   = eb + r; if (e >= E) e = E - 1;
            nid[i] = (row >> 5) ? eidx[(size_t)E + e] : eidx[e];
        }
    };
    auto load_dist = [&](int tl) -> float {
        if (t >= TILE_M) return 0.f;
        int e = tl * TILE_M + t; if (e >= E) e = E - 1;
        int s = eidx[e], d = eidx[(size_t)E + e];
        float dx = pos[3 * (size_t)s]     - pos[3 * (size_t)d];
        float dy = pos[3 * (size_t)s + 1] - pos[3 * (size_t)d + 1];
        float dz = pos[3 * (size_t)s + 2] - pos[3 * (size_t)d + 2];
        return sqrtf(dx * dx + dy * dy + dz * dz);
    };
    auto dma_issue = [&](int buf) {
        _Float16* dst = sA[buf];
        #pragma unroll
        for (int i = 0; i < 4; ++i) {
            int cid = i * 256 + t;
            int row = cid >> 4;
            int cg  = (cid & 15) ^ (row & 15);      // XOR swizzle
            const _Float16* gp = nodeEmb + (size_t)nid[i] * HID + cg * 8;
            __builtin_amdgcn_global_load_lds(
                (__attribute__((address_space(1))) void*)gp,
                (__attribute__((address_space(3))) void*)&dst[(i * 256 + (t & 192)) * 8],
                16, 0, 0);
        }
    };

    bool havePrev = false;
    int prevEbase = 0;
    int buf = 0;
    int tile = blockIdx.x;
    if (tile < nTiles) {
        load_nid(tile);
        dpre = load_dist(tile);
        dma_issue(0);
    }

    for (; tile < nTiles; tile += gridDim.x) {
        const int ebase = tile * TILE_M;
        if (t < TILE_M) sDist[t] = dpre;
        __syncthreads();                     // B1: DMA(T) drained, pf(T-1) ready

        // ---- final reduce of tile T-1 ----
        if (havePrev && t < 4 * TILE_M) {
            int m = t >> 2, n = t & 3;
            float s = pf[0][m][n] + pf[1][m][n] + pf[2][m][n] + pf[3][m][n] + b3n;
            int e = prevEbase + m;
            if (e < E) out[(size_t)e * 4 + n] = s;
        }

        // ---- issue DMA for T+1 into the other buffer (full-tile overlap) ----
        int nxt = tile + gridDim.x;
        if (nxt < nTiles) {
            load_nid(nxt);
            dpre = load_dist(nxt);
            dma_issue(buf ^ 1);
        }

        // ---- layer 1 ----
        floatx4 acc[2][2];
        #pragma unroll
        for (int ct = 0; ct < 2; ++ct)
            #pragma unroll
            for (int rt = 0; rt < 2; ++rt) {
                acc[ct][rt][0] = b1f[ct][0]; acc[ct][rt][1] = b1f[ct][1];
                acc[ct][rt][2] = b1f[ct][2]; acc[ct][rt][3] = b1f[ct][3];
            }
        const _Float16* sAc = sA[buf];
        #pragma unroll
        for (int kc = 0; kc < 8; ++kc) {
            int hf   = kc >> 2;
            int cg   = (kc & 3) * 4 + quad;
            int slot = (cg ^ l16) * 8;
            const _Float16* base = &sAc[(hf * TILE_M + l16) * HID + slot];
            half8 a0 = *(const half8*)(base + 0 * 16 * HID);
            half8 a1 = *(const half8*)(base + 1 * 16 * HID);
            acc[0][0] = __builtin_amdgcn_mfma_f32_16x16x32_f16(w1f[kc][0], a0, acc[0][0], 0, 0, 0);
            acc[0][1] = __builtin_amdgcn_mfma_f32_16x16x32_f16(w1f[kc][0], a1, acc[0][1], 0, 0, 0);
            acc[1][0] = __builtin_amdgcn_mfma_f32_16x16x32_f16(w1f[kc][1], a0, acc[1][0], 0, 0, 0);
            acc[1][1] = __builtin_amdgcn_mfma_f32_16x16x32_f16(w1f[kc][1], a1, acc[1][1], 0, 0, 0);
        }
        // epilogue 1 -> sH1 (XOR-swizzled uint2 writes)
        #pragma unroll
        for (int rt = 0; rt < 2; ++rt) {
            int m = rt * 16 + l16;
            float d = sDist[m];
            #pragma unroll
            for (int ct = 0; ct < 2; ++ct) {
                float v0 = fast_silu(fmaf(d, w1c[ct][0], acc[ct][rt][0]));
                float v1 = fast_silu(fmaf(d, w1c[ct][1], acc[ct][rt][1]));
                float v2 = fast_silu(fmaf(d, w1c[ct][2], acc[ct][rt][2]));
                float v3 = fast_silu(fmaf(d, w1c[ct][3], acc[ct][rt][3]));
                uint2 w;
                w.x = pk2(v0, v1);
                w.y = pk2(v2, v3);
                int cgb  = wave * 4 + ct * 2 + (quad >> 1);
                int slot = cgb ^ l16;
                *(uint2*)&sH1[m * HID + slot * 8 + (quad & 1) * 4] = w;
            }
        }
        barrier_lds_only();                  // B2: LDS-only; DMA stays in flight

        // ---- layer 2 ----
        floatx4 acc2[2][2];
        #pragma unroll
        for (int ct = 0; ct < 2; ++ct)
            #pragma unroll
            for (int rt = 0; rt < 2; ++rt) {
                acc2[ct][rt][0] = b2f[ct][0]; acc2[ct][rt][1] = b2f[ct][1];
                acc2[ct][rt][2] = b2f[ct][2]; acc2[ct][rt][3] = b2f[ct][3];
            }
        #pragma unroll
        for (int kc = 0; kc < 4; ++kc) {
            int slot = ((kc * 4 + quad) ^ l16) * 8;
            half8 a0 = *(const half8*)&sH1[(0 * 16 + l16) * HID + slot];
            half8 a1 = *(const half8*)&sH1[(1 * 16 + l16) * HID + slot];
            acc2[0][0] = __builtin_amdgcn_mfma_f32_16x16x32_f16(w2f[kc][0], a0, acc2[0][0], 0, 0, 0);
            acc2[0][1] = __builtin_amdgcn_mfma_f32_16x16x32_f16(w2f[kc][0], a1, acc2[0][1], 0, 0, 0);
            acc2[1][0] = __builtin_amdgcn_mfma_f32_16x16x32_f16(w2f[kc][1], a0, acc2[1][0], 0, 0, 0);
            acc2[1][1] = __builtin_amdgcn_mfma_f32_16x16x32_f16(w2f[kc][1], a1, acc2[1][1], 0, 0, 0);
        }

        // ---- layer 3 in registers ----
        #pragma unroll
        for (int rt = 0; rt < 2; ++rt) {
            int m = rt * 16 + l16;
            float p0 = 0.f, p1 = 0.f, p2 = 0.f, p3 = 0.f;
            #pragma unroll
            for (int ct = 0; ct < 2; ++ct) {
                float v0 = fast_silu(acc2[ct][rt][0]);
                float v1 = fast_silu(acc2[ct][rt][1]);
                float v2 = fast_silu(acc2[ct][rt][2]);
                float v3 = fast_silu(acc2[ct][rt][3]);
                fp16x2 hA = __builtin_amdgcn_cvt_pkrtz(v0, v1);
                fp16x2 hB = __builtin_amdgcn_cvt_pkrtz(v2, v3);
                p0 = dot2f(hA, w3h[ct][0][0], p0); p0 = dot2f(hB, w3h[ct][1][0], p0);
                p1 = dot2f(hA, w3h[ct][0][1], p1); p1 = dot2f(hB, w3h[ct][1][1], p1);
                p2 = dot2f(hA, w3h[ct][0][2], p2); p2 = dot2f(hB, w3h[ct][1][2], p2);
                p3 = dot2f(hA, w3h[ct][0][3], p3); p3 = dot2f(hB, w3h[ct][1][3], p3);
            }
            p0 += __shfl_xor(p0, 16); p0 += __shfl_xor(p0, 32);
            p1 += __shfl_xor(p1, 16); p1 += __shfl_xor(p1, 32);
            p2 += __shfl_xor(p2, 16); p2 += __shfl_xor(p2, 32);
            p3 += __shfl_xor(p3, 16); p3 += __shfl_xor(p3, 32);
            if (quad == 0) {
                float4 o = {p0, p1, p2, p3};
                *(float4*)&pf[wave][m][0] = o;
            }
        }
        havePrev = true;
        prevEbase = ebase;
        buf ^= 1;
    }

    // ---- flush: final reduce of the last tile ----
    if (havePrev) {
        __syncthreads();
        if (t < 4 * TILE_M) {
            int m = t >> 2, n = t & 3;
            float s = pf[0][m][n] + pf[1][m][n] + pf[2][m][n] + pf[3][m][n] + b3n;
            int e = prevEbase + m;
            if (e < E) out[(size_t)e * 4 + n] = s;
        }
    }
}

extern "C" void kernel_launch(void* const* d_in, const int* in_sizes, int n_in,
                              void* d_out, int out_size, void* d_ws, size_t ws_size,
                              hipStream_t stream) {
    const float* x   = (const float*)d_in[0];
    const float* pos = (const float*)d_in[1];
    const int*  eidx = (const int*)d_in[2];
    const float* Wa = (const float*)d_in[3];
    const float* ba = (const float*)d_in[4];
    const float* Wp = (const float*)d_in[5];
    const float* bp = (const float*)d_in[6];
    const float* W1 = (const float*)d_in[7];
    const float* b1 = (const float*)d_in[8];
    const float* W2 = (const float*)d_in[9];
    const float* b2 = (const float*)d_in[10];
    const float* W3 = (const float*)d_in[11];
    const float* b3 = (const float*)d_in[12];
    float* out = (float*)d_out;

    int N = in_sizes[0] / 16;   // ATOM_DIM
    int E = in_sizes[2] / 2;

    _Float16* nodeEmb = (_Float16*)d_ws;   // N*128 fp16 = 25.6 MB

    int nodeTiles = (N + 63) / 64;
    node_emb_kernel<<<nodeTiles, 256, 0, stream>>>(x, pos, Wa, ba, Wp, bp, nodeEmb, N);

    int nTiles = (E + TILE_M - 1) / TILE_M;
    edge_mlp_kernel<<<512, 256, 0, stream>>>(nodeEmb, pos, eidx,
                                             W1, b1, W2, b2, W3, b3,
                                             out, E, nTiles);
}

// Round 8
// 402.946 us; speedup vs baseline: 1.8924x; 1.0325x over previous
//
#include <hip/hip_runtime.h>
#include <hip/hip_bf16.h>
#include <hip/hip_fp16.h>

typedef _Float16 half8 __attribute__((ext_vector_type(8)));
typedef _Float16 half4 __attribute__((ext_vector_type(4)));
typedef __fp16 fp16x2 __attribute__((ext_vector_type(2)));
typedef float floatx4 __attribute__((ext_vector_type(4)));

#define HID 128
#define TILE_M 64
#define BLK 512   // 8 waves; each wave owns 16 output columns

__device__ __forceinline__ float fast_silu(float v) {
    float e = __expf(-v);
    return v * __builtin_amdgcn_rcpf(1.f + e);
}

__device__ __forceinline__ unsigned int pk2(float a, float b) {
    fp16x2 h = __builtin_amdgcn_cvt_pkrtz(a, b);
    return __builtin_bit_cast(unsigned int, h);
}

__device__ __forceinline__ float dot2f(fp16x2 a, fp16x2 b, float c) {
#if __has_builtin(__builtin_amdgcn_fdot2)
    return __builtin_amdgcn_fdot2(a, b, c, false);
#else
    return fmaf((float)a[0], (float)b[0], fmaf((float)a[1], (float)b[1], c));
#endif
}

// LDS-only barrier: drains LDS ops but leaves global_load_lds (vmcnt) in
// flight. Use ONLY where the barrier guards LDS-LDS hazards exclusively.
__device__ __forceinline__ void barrier_lds_only() {
    asm volatile("s_waitcnt lgkmcnt(0)\n\ts_barrier" ::: "memory");
}

// ---------------------------------------------------------------------------
// Kernel 1: node_emb = [x|pos|0-pad] @ [Wa;Wp;0] + (ba+bp). Block handles a
// 64-node tile via MFMA; output assembled in padded LDS, stored coalesced.
// ---------------------------------------------------------------------------
#define LDO 136
__global__ __launch_bounds__(256) void node_emb_kernel(
    const float* __restrict__ x, const float* __restrict__ pos,
    const float* __restrict__ Wa, const float* __restrict__ ba,
    const float* __restrict__ Wp, const float* __restrict__ bp,
    _Float16* __restrict__ nodeEmb, int N)
{
    __shared__ __align__(16) _Float16 sOut[64 * LDO];   // 17 KB
    const int t    = threadIdx.x;
    const int wave = t >> 6;
    const int lane = t & 63;
    const int quad = lane >> 4;
    const int l16  = lane & 15;

    half8 wf[2];
    floatx4 bias[2];
    #pragma unroll
    for (int ct = 0; ct < 2; ++ct) {
        int col = wave * 32 + ct * 16 + l16;
        #pragma unroll
        for (int j = 0; j < 8; ++j) {
            int k = quad * 8 + j;
            float w = 0.f;
            if (k < 16) w = Wa[k * HID + col];
            else if (k < 19) w = Wp[(k - 16) * HID + col];
            wf[ct][j] = (_Float16)w;
        }
        #pragma unroll
        for (int i = 0; i < 4; ++i) {
            int c2 = wave * 32 + ct * 16 + quad * 4 + i;
            bias[ct][i] = ba[c2] + bp[c2];
        }
    }

    int nTiles = (N + 63) >> 6;
    for (int tile = blockIdx.x; tile < nTiles; tile += gridDim.x) {
        int base = tile * 64;
        half8 af[4];
        #pragma unroll
        for (int rt = 0; rt < 4; ++rt) {
            int node = base + rt * 16 + l16;
            int nd = node < N ? node : N - 1;
            half8 a = (half8){0, 0, 0, 0, 0, 0, 0, 0};
            if (quad < 2) {
                const float* xp = x + (size_t)nd * 16 + quad * 8;
                float4 v0 = *(const float4*)xp;
                float4 v1 = *(const float4*)(xp + 4);
                a[0] = (_Float16)v0.x; a[1] = (_Float16)v0.y;
                a[2] = (_Float16)v0.z; a[3] = (_Float16)v0.w;
                a[4] = (_Float16)v1.x; a[5] = (_Float16)v1.y;
                a[6] = (_Float16)v1.z; a[7] = (_Float16)v1.w;
            } else if (quad == 2) {
                const float* pp = pos + (size_t)nd * 3;
                a[0] = (_Float16)pp[0]; a[1] = (_Float16)pp[1]; a[2] = (_Float16)pp[2];
            }
            af[rt] = a;
        }
        #pragma unroll
        for (int ct = 0; ct < 2; ++ct)
            #pragma unroll
            for (int rt = 0; rt < 4; ++rt) {
                floatx4 d = bias[ct];
                d = __builtin_amdgcn_mfma_f32_16x16x32_f16(wf[ct], af[rt], d, 0, 0, 0);
                half4 hv;
                hv[0] = (_Float16)d[0]; hv[1] = (_Float16)d[1];
                hv[2] = (_Float16)d[2]; hv[3] = (_Float16)d[3];
                *(half4*)&sOut[(rt * 16 + l16) * LDO + wave * 32 + ct * 16 + quad * 4] = hv;
            }
        __syncthreads();
        #pragma unroll
        for (int p = 0; p < 4; ++p) {
            int idx = p * 256 + t;
            int r = idx >> 4, c = idx & 15;
            int node = base + r;
            if (node < N)
                *(half8*)(nodeEmb + (size_t)node * HID + c * 8) =
                    *(const half8*)&sOut[r * LDO + c * 8];
        }
        __syncthreads();
    }
}

// ---------------------------------------------------------------------------
// Kernel 2: per-edge MLP. 512 threads (8 waves x 16 cols), 64 edges/tile,
// single-buffer sA with DMA issued post-B2 (lgkm-only barrier keeps it in
// flight), XOR-swizzled sA/sH1, register layer-3, deferred pf reduce.
// Register budget: ~69 resident weight regs/wave -> fits 128-cap (4 waves/EU).
// ---------------------------------------------------------------------------
__global__ __launch_bounds__(BLK, 4) void edge_mlp_kernel(
    const _Float16* __restrict__ nodeEmb,
    const float* __restrict__ pos,
    const int* __restrict__ eidx,          // [2][E]
    const float* __restrict__ W1, const float* __restrict__ b1,   // [257][128]
    const float* __restrict__ W2, const float* __restrict__ b2,   // [128][128]
    const float* __restrict__ W3, const float* __restrict__ b3,   // [128][4]
    float* __restrict__ out, int E, int nTiles)
{
    __shared__ __align__(16) _Float16 sA[2 * TILE_M * HID];   // 32 KB, XOR swizzle
    __shared__ __align__(16) _Float16 sH1[TILE_M * HID];      // 16 KB, XOR swizzle
    __shared__ float pf[8][TILE_M][4];                        // 8 KB partials
    __shared__ float sDist[TILE_M];

    const int t    = threadIdx.x;
    const int wave = t >> 6;
    const int lane = t & 63;
    const int quad = lane >> 4;
    const int l16  = lane & 15;
    const int colbase = wave * 16;        // each wave owns 16 output columns

    // ---- weight fragments (per-wave 16-col slice) ----
    half8 w1f[8];
    half8 w2f[4];
    fp16x2 w3h[2][4];
    float w1c[4], b1f[4], b2f[4];
    {
        int col = colbase + l16;
        #pragma unroll
        for (int kc = 0; kc < 8; ++kc)
            #pragma unroll
            for (int j = 0; j < 8; ++j)
                w1f[kc][j] = (_Float16)W1[(kc * 32 + quad * 8 + j) * HID + col];
        #pragma unroll
        for (int kc = 0; kc < 4; ++kc)
            #pragma unroll
            for (int j = 0; j < 8; ++j)
                w2f[kc][j] = (_Float16)W2[(kc * 32 + quad * 8 + j) * HID + col];
        #pragma unroll
        for (int i = 0; i < 4; ++i) {
            int c2 = colbase + quad * 4 + i;
            w1c[i] = W1[256 * HID + c2];
            b1f[i] = b1[c2];
            b2f[i] = b2[c2];
        }
        #pragma unroll
        for (int pr = 0; pr < 2; ++pr) {
            int c0 = colbase + quad * 4 + pr * 2;
            #pragma unroll
            for (int n = 0; n < 4; ++n) {
                fp16x2 h;
                h[0] = (__fp16)W3[c0 * 4 + n];
                h[1] = (__fp16)W3[(c0 + 1) * 4 + n];
                w3h[pr][n] = h;
            }
        }
    }
    const float b3n = b3[t & 3];

    int nid[4];
    float dpre = 0.f;

    auto load_nid = [&](int tl) {
        int eb = tl * TILE_M;
        #pragma unroll
        for (int i = 0; i < 4; ++i) {
            int cid = i * BLK + t;           // 0..2047 chunks
            int row = cid >> 4;              // 0..127: 0-63 src, 64-127 dst
            int r   = row & 63;
            int e   = eb + r; if (e >= E) e = E - 1;
            nid[i] = (row >> 6) ? eidx[(size_t)E + e] : eidx[e];
        }
    };
    auto load_dist = [&](int tl) -> float {
        if (t >= TILE_M) return 0.f;
        int e = tl * TILE_M + t; if (e >= E) e = E - 1;
        int s = eidx[e], d = eidx[(size_t)E + e];
        float dx = pos[3 * (size_t)s]     - pos[3 * (size_t)d];
        float dy = pos[3 * (size_t)s + 1] - pos[3 * (size_t)d + 1];
        float dz = pos[3 * (size_t)s + 2] - pos[3 * (size_t)d + 2];
        return sqrtf(dx * dx + dy * dy + dz * dz);
    };
    auto dma_issue = [&]() {
        #pragma unroll
        for (int i = 0; i < 4; ++i) {
            int cid = i * BLK + t;
            int row = cid >> 4;
            int cg  = (cid & 15) ^ (row & 15);      // XOR swizzle
            const _Float16* gp = nodeEmb + (size_t)nid[i] * HID + cg * 8;
            __builtin_amdgcn_global_load_lds(
                (__attribute__((address_space(1))) void*)gp,
                (__attribute__((address_space(3))) void*)&sA[(i * BLK + (t & 448)) * 8],
                16, 0, 0);
        }
    };

    bool havePrev = false;
    int prevEbase = 0;
    int tile = blockIdx.x;
    if (tile < nTiles) {
        load_nid(tile);
        dpre = load_dist(tile);
        dma_issue();                         // drains at first B1
    }

    for (; tile < nTiles; tile += gridDim.x) {
        const int ebase = tile * TILE_M;
        if (t < TILE_M) sDist[t] = dpre;
        __syncthreads();                     // B1: DMA(T) drained, pf(T-1) ready

        // ---- final reduce of tile T-1 (256 outputs) ----
        if (havePrev && t < 4 * TILE_M) {
            int m = t >> 2, n = t & 3;
            float s = pf[0][m][n] + pf[1][m][n] + pf[2][m][n] + pf[3][m][n]
                    + pf[4][m][n] + pf[5][m][n] + pf[6][m][n] + pf[7][m][n] + b3n;
            int e = prevEbase + m;
            if (e < E) out[(size_t)e * 4 + n] = s;
        }

        // ---- prefetch next tile metadata (DMA issued post-B2) ----
        int nxt = tile + gridDim.x;
        if (nxt < nTiles) {
            load_nid(nxt);
            dpre = load_dist(nxt);
        }

        // ---- layer 1: 8 kc x 4 rt MFMAs, bias in acc init ----
        floatx4 acc[4];
        #pragma unroll
        for (int rt = 0; rt < 4; ++rt) {
            acc[rt][0] = b1f[0]; acc[rt][1] = b1f[1];
            acc[rt][2] = b1f[2]; acc[rt][3] = b1f[3];
        }
        #pragma unroll
        for (int kc = 0; kc < 8; ++kc) {
            int hf   = kc >> 2;
            int cg   = (kc & 3) * 4 + quad;
            int slot = (cg ^ l16) * 8;
            const _Float16* base = &sA[(hf * TILE_M + l16) * HID + slot];
            half8 a0 = *(const half8*)(base + 0 * 16 * HID);
            half8 a1 = *(const half8*)(base + 1 * 16 * HID);
            half8 a2 = *(const half8*)(base + 2 * 16 * HID);
            half8 a3 = *(const half8*)(base + 3 * 16 * HID);
            acc[0] = __builtin_amdgcn_mfma_f32_16x16x32_f16(w1f[kc], a0, acc[0], 0, 0, 0);
            acc[1] = __builtin_amdgcn_mfma_f32_16x16x32_f16(w1f[kc], a1, acc[1], 0, 0, 0);
            acc[2] = __builtin_amdgcn_mfma_f32_16x16x32_f16(w1f[kc], a2, acc[2], 0, 0, 0);
            acc[3] = __builtin_amdgcn_mfma_f32_16x16x32_f16(w1f[kc], a3, acc[3], 0, 0, 0);
        }
        // epilogue 1 -> sH1 (XOR-swizzled uint2 writes)
        #pragma unroll
        for (int rt = 0; rt < 4; ++rt) {
            int m = rt * 16 + l16;
            float d = sDist[m];
            float v0 = fast_silu(fmaf(d, w1c[0], acc[rt][0]));
            float v1 = fast_silu(fmaf(d, w1c[1], acc[rt][1]));
            float v2 = fast_silu(fmaf(d, w1c[2], acc[rt][2]));
            float v3 = fast_silu(fmaf(d, w1c[3], acc[rt][3]));
            uint2 w;
            w.x = pk2(v0, v1);
            w.y = pk2(v2, v3);
            int cgb  = wave * 2 + (quad >> 1);      // chunk of col group
            int slot = cgb ^ l16;
            *(uint2*)&sH1[m * HID + slot * 8 + (quad & 1) * 4] = w;
        }
        barrier_lds_only();                  // B2: LDS-only; no vmcnt drain

        // ---- async DMA for next tile (sA free; overlaps L2+L3+next B1) ----
        if (nxt < nTiles) dma_issue();

        // ---- layer 2 ----
        floatx4 acc2[4];
        #pragma unroll
        for (int rt = 0; rt < 4; ++rt) {
            acc2[rt][0] = b2f[0]; acc2[rt][1] = b2f[1];
            acc2[rt][2] = b2f[2]; acc2[rt][3] = b2f[3];
        }
        #pragma unroll
        for (int kc = 0; kc < 4; ++kc) {
            int slot = ((kc * 4 + quad) ^ l16) * 8;
            half8 a0 = *(const half8*)&sH1[(0 * 16 + l16) * HID + slot];
            half8 a1 = *(const half8*)&sH1[(1 * 16 + l16) * HID + slot];
            half8 a2 = *(const half8*)&sH1[(2 * 16 + l16) * HID + slot];
            half8 a3 = *(const half8*)&sH1[(3 * 16 + l16) * HID + slot];
            acc2[0] = __builtin_amdgcn_mfma_f32_16x16x32_f16(w2f[kc], a0, acc2[0], 0, 0, 0);
            acc2[1] = __builtin_amdgcn_mfma_f32_16x16x32_f16(w2f[kc], a1, acc2[1], 0, 0, 0);
            acc2[2] = __builtin_amdgcn_mfma_f32_16x16x32_f16(w2f[kc], a2, acc2[2], 0, 0, 0);
            acc2[3] = __builtin_amdgcn_mfma_f32_16x16x32_f16(w2f[kc], a3, acc2[3], 0, 0, 0);
        }

        // ---- layer 3 in registers: silu -> dot2 -> quad shfl reduce -> pf ----
        #pragma unroll
        for (int rt = 0; rt < 4; ++rt) {
            int m = rt * 16 + l16;
            float v0 = fast_silu(acc2[rt][0]);
            float v1 = fast_silu(acc2[rt][1]);
            float v2 = fast_silu(acc2[rt][2]);
            float v3 = fast_silu(acc2[rt][3]);
            fp16x2 hA = __builtin_amdgcn_cvt_pkrtz(v0, v1);
            fp16x2 hB = __builtin_amdgcn_cvt_pkrtz(v2, v3);
            float p0 = dot2f(hA, w3h[0][0], 0.f); p0 = dot2f(hB, w3h[1][0], p0);
            float p1 = dot2f(hA, w3h[0][1], 0.f); p1 = dot2f(hB, w3h[1][1], p1);
            float p2 = dot2f(hA, w3h[0][2], 0.f); p2 = dot2f(hB, w3h[1][2], p2);
            float p3 = dot2f(hA, w3h[0][3], 0.f); p3 = dot2f(hB, w3h[1][3], p3);
            p0 += __shfl_xor(p0, 16); p0 += __shfl_xor(p0, 32);
            p1 += __shfl_xor(p1, 16); p1 += __shfl_xor(p1, 32);
            p2 += __shfl_xor(p2, 16); p2 += __shfl_xor(p2, 32);
            p3 += __shfl_xor(p3, 16); p3 += __shfl_xor(p3, 32);
            if (quad == 0) {
                float4 o = {p0, p1, p2, p3};
                *(float4*)&pf[wave][m][0] = o;
            }
        }
        havePrev = true;
        prevEbase = ebase;
    }

    // ---- flush: final reduce of the last tile ----
    if (havePrev) {
        __syncthreads();
        if (t < 4 * TILE_M) {
            int m = t >> 2, n = t & 3;
            float s = pf[0][m][n] + pf[1][m][n] + pf[2][m][n] + pf[3][m][n]
                    + pf[4][m][n] + pf[5][m][n] + pf[6][m][n] + pf[7][m][n] + b3n;
            int e = prevEbase + m;
            if (e < E) out[(size_t)e * 4 + n] = s;
        }
    }
}

extern "C" void kernel_launch(void* const* d_in, const int* in_sizes, int n_in,
                              void* d_out, int out_size, void* d_ws, size_t ws_size,
                              hipStream_t stream) {
    const float* x   = (const float*)d_in[0];
    const float* pos = (const float*)d_in[1];
    const int*  eidx = (const int*)d_in[2];
    const float* Wa = (const float*)d_in[3];
    const float* ba = (const float*)d_in[4];
    const float* Wp = (const float*)d_in[5];
    const float* bp = (const float*)d_in[6];
    const float* W1 = (const float*)d_in[7];
    const float* b1 = (const float*)d_in[8];
    const float* W2 = (const float*)d_in[9];
    const float* b2 = (const float*)d_in[10];
    const float* W3 = (const float*)d_in[11];
    const float* b3 = (const float*)d_in[12];
    float* out = (float*)d_out;

    int N = in_sizes[0] / 16;   // ATOM_DIM
    int E = in_sizes[2] / 2;

    _Float16* nodeEmb = (_Float16*)d_ws;   // N*128 fp16 = 25.6 MB

    int nodeTiles = (N + 63) / 64;
    node_emb_kernel<<<nodeTiles, 256, 0, stream>>>(x, pos, Wa, ba, Wp, bp, nodeEmb, N);

    int nTiles = (E + TILE_M - 1) / TILE_M;
    edge_mlp_kernel<<<512, BLK, 0, stream>>>(nodeEmb, pos, eidx,
                                             W1, b1, W2, b2, W3, b3,
                                             out, E, nTiles);
}

// Round 9
// 343.419 us; speedup vs baseline: 2.2204x; 1.1733x over previous
//
#include <hip/hip_runtime.h>
#include <hip/hip_bf16.h>
#include <hip/hip_fp16.h>

typedef _Float16 half8 __attribute__((ext_vector_type(8)));
typedef _Float16 half4 __attribute__((ext_vector_type(4)));
typedef __fp16 fp16x2 __attribute__((ext_vector_type(2)));
typedef float floatx4 __attribute__((ext_vector_type(4)));

#define HID 128
#define TILE_M 64

__device__ __forceinline__ float fast_silu(float v) {
    float e = __expf(-v);
    return v * __builtin_amdgcn_rcpf(1.f + e);
}

__device__ __forceinline__ unsigned int pk2(float a, float b) {
    fp16x2 h = __builtin_amdgcn_cvt_pkrtz(a, b);
    return __builtin_bit_cast(unsigned int, h);
}

// LDS-only barrier: drains LDS ops but leaves global (vmcnt) traffic in
// flight. Use ONLY where the barrier guards LDS-LDS hazards exclusively.
__device__ __forceinline__ void barrier_lds_only() {
    asm volatile("s_waitcnt lgkmcnt(0)\n\ts_barrier" ::: "memory");
}

// ---------------------------------------------------------------------------
// Kernel 1: node_emb = [x|pos|0-pad] @ [Wa;Wp;0] + (ba+bp). Block handles a
// 64-node tile via MFMA; output assembled in padded LDS, stored coalesced.
// ---------------------------------------------------------------------------
#define LDO 136
__global__ __launch_bounds__(256) void node_emb_kernel(
    const float* __restrict__ x, const float* __restrict__ pos,
    const float* __restrict__ Wa, const float* __restrict__ ba,
    const float* __restrict__ Wp, const float* __restrict__ bp,
    _Float16* __restrict__ nodeEmb, int N)
{
    __shared__ __align__(16) _Float16 sOut[64 * LDO];   // 17 KB
    const int t    = threadIdx.x;
    const int wave = t >> 6;
    const int lane = t & 63;
    const int quad = lane >> 4;
    const int l16  = lane & 15;

    half8 wf[2];
    floatx4 bias[2];
    #pragma unroll
    for (int ct = 0; ct < 2; ++ct) {
        int col = wave * 32 + ct * 16 + l16;
        #pragma unroll
        for (int j = 0; j < 8; ++j) {
            int k = quad * 8 + j;
            float w = 0.f;
            if (k < 16) w = Wa[k * HID + col];
            else if (k < 19) w = Wp[(k - 16) * HID + col];
            wf[ct][j] = (_Float16)w;
        }
        #pragma unroll
        for (int i = 0; i < 4; ++i) {
            int c2 = wave * 32 + ct * 16 + quad * 4 + i;
            bias[ct][i] = ba[c2] + bp[c2];
        }
    }

    int nTiles = (N + 63) >> 6;
    for (int tile = blockIdx.x; tile < nTiles; tile += gridDim.x) {
        int base = tile * 64;
        half8 af[4];
        #pragma unroll
        for (int rt = 0; rt < 4; ++rt) {
            int node = base + rt * 16 + l16;
            int nd = node < N ? node : N - 1;
            half8 a = (half8){0, 0, 0, 0, 0, 0, 0, 0};
            if (quad < 2) {
                const float* xp = x + (size_t)nd * 16 + quad * 8;
                float4 v0 = *(const float4*)xp;
                float4 v1 = *(const float4*)(xp + 4);
                a[0] = (_Float16)v0.x; a[1] = (_Float16)v0.y;
                a[2] = (_Float16)v0.z; a[3] = (_Float16)v0.w;
                a[4] = (_Float16)v1.x; a[5] = (_Float16)v1.y;
                a[6] = (_Float16)v1.z; a[7] = (_Float16)v1.w;
            } else if (quad == 2) {
                const float* pp = pos + (size_t)nd * 3;
                a[0] = (_Float16)pp[0]; a[1] = (_Float16)pp[1]; a[2] = (_Float16)pp[2];
            }
            af[rt] = a;
        }
        #pragma unroll
        for (int ct = 0; ct < 2; ++ct)
            #pragma unroll
            for (int rt = 0; rt < 4; ++rt) {
                floatx4 d = bias[ct];
                d = __builtin_amdgcn_mfma_f32_16x16x32_f16(wf[ct], af[rt], d, 0, 0, 0);
                half4 hv;
                hv[0] = (_Float16)d[0]; hv[1] = (_Float16)d[1];
                hv[2] = (_Float16)d[2]; hv[3] = (_Float16)d[3];
                *(half4*)&sOut[(rt * 16 + l16) * LDO + wave * 32 + ct * 16 + quad * 4] = hv;
            }
        __syncthreads();
        #pragma unroll
        for (int p = 0; p < 4; ++p) {
            int idx = p * 256 + t;
            int r = idx >> 4, c = idx & 15;
            int node = base + r;
            if (node < N)
                *(half8*)(nodeEmb + (size_t)node * HID + c * 8) =
                    *(const half8*)&sOut[r * LDO + c * 8];
        }
        __syncthreads();
    }
}

// ---------------------------------------------------------------------------
// Kernel 2: per-edge MLP. 256 threads (4 waves x 32 cols -- the LDS-traffic
// optimum that fits registers), 64 edges/tile, async DMA gathers into
// XOR-swizzled sA, lgkm-only B2, deferred MFMA layer-3 via sH2.
// LDS 64.3 KB -> 2 blocks/CU; VGPR ~130, no spill at (256,2).
// ---------------------------------------------------------------------------
__global__ __launch_bounds__(256, 2) void edge_mlp_kernel(
    const _Float16* __restrict__ nodeEmb,
    const float* __restrict__ pos,
    const int* __restrict__ eidx,          // [2][E]
    const float* __restrict__ W1, const float* __restrict__ b1,   // [257][128]
    const float* __restrict__ W2, const float* __restrict__ b2,   // [128][128]
    const float* __restrict__ W3, const float* __restrict__ b3,   // [128][4]
    float* __restrict__ out, int E, int nTiles)
{
    __shared__ __align__(16) _Float16 sA[2 * TILE_M * HID];   // 32 KB, XOR swizzle
    __shared__ __align__(16) _Float16 sH1[TILE_M * HID];      // 16 KB, XOR swizzle
    __shared__ __align__(16) _Float16 sH2[TILE_M * HID];      // 16 KB, XOR swizzle
    __shared__ float sDist[TILE_M];

    const int t    = threadIdx.x;
    const int wave = t >> 6;
    const int lane = t & 63;
    const int quad = lane >> 4;
    const int l16  = lane & 15;
    const int colbase = wave * 32;        // each wave owns 32 output columns

    // ---- weight fragments (frag[j] = W[k0+quad*8+j][col]) ----
    half8 w1f[8][2];
    half8 w2f[4][2];
    half8 w3f[4];
    float w1c[2][4], b1f[2][4], b2f[2][4];
    #pragma unroll
    for (int ct = 0; ct < 2; ++ct) {
        int col = colbase + ct * 16 + l16;
        #pragma unroll
        for (int kc = 0; kc < 8; ++kc)
            #pragma unroll
            for (int j = 0; j < 8; ++j)
                w1f[kc][ct][j] = (_Float16)W1[(kc * 32 + quad * 8 + j) * HID + col];
        #pragma unroll
        for (int kc = 0; kc < 4; ++kc)
            #pragma unroll
            for (int j = 0; j < 8; ++j)
                w2f[kc][ct][j] = (_Float16)W2[(kc * 32 + quad * 8 + j) * HID + col];
        #pragma unroll
        for (int i = 0; i < 4; ++i) {
            int c2 = colbase + ct * 16 + quad * 4 + i;
            w1c[ct][i] = W1[256 * HID + c2];
            b1f[ct][i] = b1[c2];
            b2f[ct][i] = b2[c2];
        }
    }
    #pragma unroll
    for (int kc = 0; kc < 4; ++kc)
        #pragma unroll
        for (int j = 0; j < 8; ++j)
            w3f[kc][j] = (_Float16)W3[(kc * 32 + quad * 8 + j) * 4 + (l16 & 3)];
    const float b3v0 = b3[0], b3v1 = b3[1], b3v2 = b3[2], b3v3 = b3[3];

    int nid[8];
    float dpre = 0.f;

    auto load_nid = [&](int tl) {
        int eb = tl * TILE_M;
        #pragma unroll
        for (int i = 0; i < 8; ++i) {
            int cid = i * 256 + t;           // 0..2047 chunks of 16B
            int row = cid >> 4;              // 0..127: 0-63 src, 64-127 dst
            int r   = row & 63;
            int e   = eb + r; if (e >= E) e = E - 1;
            nid[i] = (row >> 6) ? eidx[(size_t)E + e] : eidx[e];
        }
    };
    auto load_dist = [&](int tl) -> float {
        if (t >= TILE_M) return 0.f;
        int e = tl * TILE_M + t; if (e >= E) e = E - 1;
        int s = eidx[e], d = eidx[(size_t)E + e];
        float dx = pos[3 * (size_t)s]     - pos[3 * (size_t)d];
        float dy = pos[3 * (size_t)s + 1] - pos[3 * (size_t)d + 1];
        float dz = pos[3 * (size_t)s + 2] - pos[3 * (size_t)d + 2];
        return sqrtf(dx * dx + dy * dy + dz * dz);
    };
    auto dma_issue = [&]() {
        #pragma unroll
        for (int i = 0; i < 8; ++i) {
            int cid = i * 256 + t;
            int row = cid >> 4;
            int cg  = (cid & 15) ^ (row & 15);      // XOR swizzle
            const _Float16* gp = nodeEmb + (size_t)nid[i] * HID + cg * 8;
            __builtin_amdgcn_global_load_lds(
                (__attribute__((address_space(1))) void*)gp,
                (__attribute__((address_space(3))) void*)&sA[(i * 256 + (t & 192)) * 8],
                16, 0, 0);
        }
    };

    bool havePrev = false;
    int prevEbase = 0;
    int tile = blockIdx.x;
    if (tile < nTiles) {
        load_nid(tile);
        dpre = load_dist(tile);
        dma_issue();                         // drains at first B1
    }

    for (; tile < nTiles; tile += gridDim.x) {
        const int ebase = tile * TILE_M;
        if (t < TILE_M) sDist[t] = dpre;
        __syncthreads();                     // B1: DMA(T) drained, sH2(T-1) ready

        // ---- layer 3 of previous tile: MFMA from sH2, float4 store ----
        if (havePrev) {
            floatx4 acc3 = (floatx4){0.f, 0.f, 0.f, 0.f};
            #pragma unroll
            for (int kc = 0; kc < 4; ++kc) {
                int slot = ((kc * 4 + quad) ^ l16) * 8;
                half8 h = *(const half8*)&sH2[(wave * 16 + l16) * HID + slot];
                acc3 = __builtin_amdgcn_mfma_f32_16x16x32_f16(w3f[kc], h, acc3, 0, 0, 0);
            }
            if (quad == 0) {
                int e = prevEbase + wave * 16 + l16;
                if (e < E) {
                    float4 o = {acc3[0] + b3v0, acc3[1] + b3v1,
                                acc3[2] + b3v2, acc3[3] + b3v3};
                    *(float4*)&out[(size_t)e * 4] = o;
                }
            }
        }

        // ---- prefetch next tile metadata (DMA issued post-B2) ----
        int nxt = tile + gridDim.x;
        if (nxt < nTiles) {
            load_nid(nxt);
            dpre = load_dist(nxt);
        }

        // ---- layer 1: bias in acc init, XOR-swizzled sA reads ----
        floatx4 acc[2][4];
        #pragma unroll
        for (int ct = 0; ct < 2; ++ct)
            #pragma unroll
            for (int rt = 0; rt < 4; ++rt) {
                acc[ct][rt][0] = b1f[ct][0]; acc[ct][rt][1] = b1f[ct][1];
                acc[ct][rt][2] = b1f[ct][2]; acc[ct][rt][3] = b1f[ct][3];
            }
        #pragma unroll
        for (int kc = 0; kc < 8; ++kc) {
            int hf   = kc >> 2;
            int cg   = (kc & 3) * 4 + quad;
            int slot = (cg ^ l16) * 8;
            const _Float16* base = &sA[(hf * TILE_M + l16) * HID + slot];
            half8 a0 = *(const half8*)(base + 0 * 16 * HID);
            half8 a1 = *(const half8*)(base + 1 * 16 * HID);
            half8 a2 = *(const half8*)(base + 2 * 16 * HID);
            half8 a3 = *(const half8*)(base + 3 * 16 * HID);
            acc[0][0] = __builtin_amdgcn_mfma_f32_16x16x32_f16(w1f[kc][0], a0, acc[0][0], 0, 0, 0);
            acc[0][1] = __builtin_amdgcn_mfma_f32_16x16x32_f16(w1f[kc][0], a1, acc[0][1], 0, 0, 0);
            acc[0][2] = __builtin_amdgcn_mfma_f32_16x16x32_f16(w1f[kc][0], a2, acc[0][2], 0, 0, 0);
            acc[0][3] = __builtin_amdgcn_mfma_f32_16x16x32_f16(w1f[kc][0], a3, acc[0][3], 0, 0, 0);
            acc[1][0] = __builtin_amdgcn_mfma_f32_16x16x32_f16(w1f[kc][1], a0, acc[1][0], 0, 0, 0);
            acc[1][1] = __builtin_amdgcn_mfma_f32_16x16x32_f16(w1f[kc][1], a1, acc[1][1], 0, 0, 0);
            acc[1][2] = __builtin_amdgcn_mfma_f32_16x16x32_f16(w1f[kc][1], a2, acc[1][2], 0, 0, 0);
            acc[1][3] = __builtin_amdgcn_mfma_f32_16x16x32_f16(w1f[kc][1], a3, acc[1][3], 0, 0, 0);
        }
        // epilogue 1 -> sH1 (XOR-swizzled uint2 writes)
        #pragma unroll
        for (int rt = 0; rt < 4; ++rt) {
            int m = rt * 16 + l16;
            float d = sDist[m];
            #pragma unroll
            for (int ct = 0; ct < 2; ++ct) {
                float v0 = fast_silu(fmaf(d, w1c[ct][0], acc[ct][rt][0]));
                float v1 = fast_silu(fmaf(d, w1c[ct][1], acc[ct][rt][1]));
                float v2 = fast_silu(fmaf(d, w1c[ct][2], acc[ct][rt][2]));
                float v3 = fast_silu(fmaf(d, w1c[ct][3], acc[ct][rt][3]));
                uint2 w;
                w.x = pk2(v0, v1);
                w.y = pk2(v2, v3);
                int cgb  = wave * 4 + ct * 2 + (quad >> 1);
                int slot = cgb ^ l16;
                *(uint2*)&sH1[m * HID + slot * 8 + (quad & 1) * 4] = w;
            }
        }
        barrier_lds_only();                  // B2: LDS-only; prefetch loads live

        // ---- async DMA for next tile (sA free; overlaps L2+L3+next B1) ----
        if (nxt < nTiles) dma_issue();

        // ---- layer 2 ----
        floatx4 acc2[2][4];
        #pragma unroll
        for (int ct = 0; ct < 2; ++ct)
            #pragma unroll
            for (int rt = 0; rt < 4; ++rt) {
                acc2[ct][rt][0] = b2f[ct][0]; acc2[ct][rt][1] = b2f[ct][1];
                acc2[ct][rt][2] = b2f[ct][2]; acc2[ct][rt][3] = b2f[ct][3];
            }
        #pragma unroll
        for (int kc = 0; kc < 4; ++kc) {
            int slot = ((kc * 4 + quad) ^ l16) * 8;
            half8 a0 = *(const half8*)&sH1[(0 * 16 + l16) * HID + slot];
            half8 a1 = *(const half8*)&sH1[(1 * 16 + l16) * HID + slot];
            half8 a2 = *(const half8*)&sH1[(2 * 16 + l16) * HID + slot];
            half8 a3 = *(const half8*)&sH1[(3 * 16 + l16) * HID + slot];
            acc2[0][0] = __builtin_amdgcn_mfma_f32_16x16x32_f16(w2f[kc][0], a0, acc2[0][0], 0, 0, 0);
            acc2[0][1] = __builtin_amdgcn_mfma_f32_16x16x32_f16(w2f[kc][0], a1, acc2[0][1], 0, 0, 0);
            acc2[0][2] = __builtin_amdgcn_mfma_f32_16x16x32_f16(w2f[kc][0], a2, acc2[0][2], 0, 0, 0);
            acc2[0][3] = __builtin_amdgcn_mfma_f32_16x16x32_f16(w2f[kc][0], a3, acc2[0][3], 0, 0, 0);
            acc2[1][0] = __builtin_amdgcn_mfma_f32_16x16x32_f16(w2f[kc][1], a0, acc2[1][0], 0, 0, 0);
            acc2[1][1] = __builtin_amdgcn_mfma_f32_16x16x32_f16(w2f[kc][1], a1, acc2[1][1], 0, 0, 0);
            acc2[1][2] = __builtin_amdgcn_mfma_f32_16x16x32_f16(w2f[kc][1], a2, acc2[1][2], 0, 0, 0);
            acc2[1][3] = __builtin_amdgcn_mfma_f32_16x16x32_f16(w2f[kc][1], a3, acc2[1][3], 0, 0, 0);
        }
        // epilogue 2 -> sH2 (L3(T-1) reads finished pre-B2)
        #pragma unroll
        for (int rt = 0; rt < 4; ++rt) {
            int m = rt * 16 + l16;
            #pragma unroll
            for (int ct = 0; ct < 2; ++ct) {
                float v0 = fast_silu(acc2[ct][rt][0]);
                float v1 = fast_silu(acc2[ct][rt][1]);
                float v2 = fast_silu(acc2[ct][rt][2]);
                float v3 = fast_silu(acc2[ct][rt][3]);
                uint2 w;
                w.x = pk2(v0, v1);
                w.y = pk2(v2, v3);
                int cgb  = wave * 4 + ct * 2 + (quad >> 1);
                int slot = cgb ^ l16;
                *(uint2*)&sH2[m * HID + slot * 8 + (quad & 1) * 4] = w;
            }
        }
        havePrev = true;
        prevEbase = ebase;
    }

    // ---- flush: layer 3 of the final tile ----
    if (havePrev) {
        __syncthreads();
        floatx4 acc3 = (floatx4){0.f, 0.f, 0.f, 0.f};
        #pragma unroll
        for (int kc = 0; kc < 4; ++kc) {
            int slot = ((kc * 4 + quad) ^ l16) * 8;
            half8 h = *(const half8*)&sH2[(wave * 16 + l16) * HID + slot];
            acc3 = __builtin_amdgcn_mfma_f32_16x16x32_f16(w3f[kc], h, acc3, 0, 0, 0);
        }
        if (quad == 0) {
            int e = prevEbase + wave * 16 + l16;
            if (e < E) {
                float4 o = {acc3[0] + b3v0, acc3[1] + b3v1,
                            acc3[2] + b3v2, acc3[3] + b3v3};
                *(float4*)&out[(size_t)e * 4] = o;
            }
        }
    }
}

extern "C" void kernel_launch(void* const* d_in, const int* in_sizes, int n_in,
                              void* d_out, int out_size, void* d_ws, size_t ws_size,
                              hipStream_t stream) {
    const float* x   = (const float*)d_in[0];
    const float* pos = (const float*)d_in[1];
    const int*  eidx = (const int*)d_in[2];
    const float* Wa = (const float*)d_in[3];
    const float* ba = (const float*)d_in[4];
    const float* Wp = (const float*)d_in[5];
    const float* bp = (const float*)d_in[6];
    const float* W1 = (const float*)d_in[7];
    const float* b1 = (const float*)d_in[8];
    const float* W2 = (const float*)d_in[9];
    const float* b2 = (const float*)d_in[10];
    const float* W3 = (const float*)d_in[11];
    const float* b3 = (const float*)d_in[12];
    float* out = (float*)d_out;

    int N = in_sizes[0] / 16;   // ATOM_DIM
    int E = in_sizes[2] / 2;

    _Float16* nodeEmb = (_Float16*)d_ws;   // N*128 fp16 = 25.6 MB

    int nodeTiles = (N + 63) / 64;
    node_emb_kernel<<<nodeTiles, 256, 0, stream>>>(x, pos, Wa, ba, Wp, bp, nodeEmb, N);

    int nTiles = (E + TILE_M - 1) / TILE_M;
    edge_mlp_kernel<<<512, 256, 0, stream>>>(nodeEmb, pos, eidx,
                                             W1, b1, W2, b2, W3, b3,
                                             out, E, nTiles);
}